// Round 9
// baseline (96.365 us; speedup 1.0000x reference)
//
#include <hip/hip_runtime.h>
#include <hip/hip_bf16.h>
#include <math.h>

#define T_STEPS 64
#define BATCH   256
#define NX      512
#define NH      512

typedef short bf16x8 __attribute__((ext_vector_type(8)));
typedef float f32x4  __attribute__((ext_vector_type(4)));

// ---------------------------------------------------------------------------
// Kernel 1: P[r][h] = b1[h] + sum_k X[r][k] * W1[h][k]   (bf16 MFMA, f32 acc)
//   (unchanged — verified rounds 3-8)
// ---------------------------------------------------------------------------
__global__ __launch_bounds__(256, 4) void gemm_bf16_kernel(
    const float* __restrict__ X,    // [16384][512]
    const float* __restrict__ W1,   // [512][512]
    const float* __restrict__ b1,   // [512]
    float* __restrict__ P)          // [16384][512]
{
    __shared__ unsigned short lds[16384];   // 32 KB: A = [0,8192), B = [8192,16384)

    const int tid  = threadIdx.x;
    const int lane = tid & 63;
    const int wave = tid >> 6;
    const int wm   = wave >> 1;
    const int wn   = wave & 1;
    const int rbase = blockIdx.x * 128;
    const int nbase = blockIdx.y * 128;

    f32x4 acc[4][4] = {};

    for (int kb = 0; kb < 512; kb += 64) {
#pragma unroll
        for (int i = 0; i < 8; ++i) {
            int g   = tid + (i & 3) * 256;
            int ks  = g >> 9;
            int ms  = (g >> 6) & 7;
            int l   = g & 63;
            int row = ms * 16 + (l & 15);
            int kof = kb + ks * 32 + (l >> 4) * 8;
            const float* src = (i < 4) ? &X[(size_t)(rbase + row) * 512 + kof]
                                       : &W1[(size_t)(nbase + row) * 512 + kof];
            float4 v0 = *(const float4*)src;
            float4 v1 = *(const float4*)(src + 4);
            union { __hip_bfloat162 q[4]; int4 pk; } u;
            u.q[0] = __float22bfloat162_rn(make_float2(v0.x, v0.y));
            u.q[1] = __float22bfloat162_rn(make_float2(v0.z, v0.w));
            u.q[2] = __float22bfloat162_rn(make_float2(v1.x, v1.y));
            u.q[3] = __float22bfloat162_rn(make_float2(v1.z, v1.w));
            *(int4*)&lds[((i < 4) ? 0 : 8192) + g * 8] = u.pk;
        }
        __syncthreads();

#pragma unroll
        for (int ks = 0; ks < 2; ++ks) {
            bf16x8 afr[4], bfr[4];
#pragma unroll
            for (int mf = 0; mf < 4; ++mf)
                afr[mf] = *(const bf16x8*)&lds[((ks * 8 + wm * 4 + mf) * 64 + lane) * 8];
#pragma unroll
            for (int nf = 0; nf < 4; ++nf)
                bfr[nf] = *(const bf16x8*)&lds[8192 + ((ks * 8 + wn * 4 + nf) * 64 + lane) * 8];
#pragma unroll
            for (int mf = 0; mf < 4; ++mf)
#pragma unroll
                for (int nf = 0; nf < 4; ++nf)
                    acc[mf][nf] = __builtin_amdgcn_mfma_f32_16x16x32_bf16(
                        afr[mf], bfr[nf], acc[mf][nf], 0, 0, 0);
        }
        __syncthreads();
    }

    float bc[4];
#pragma unroll
    for (int nf = 0; nf < 4; ++nf)
        bc[nf] = b1[nbase + wn * 64 + nf * 16 + (lane & 15)];
#pragma unroll
    for (int mf = 0; mf < 4; ++mf) {
#pragma unroll
        for (int nf = 0; nf < 4; ++nf) {
#pragma unroll
            for (int r = 0; r < 4; ++r) {
                int m = rbase + wm * 64 + mf * 16 + ((lane >> 4) << 2) + r;
                int n = nbase + wn * 64 + nf * 16 + (lane & 15);
                P[(size_t)m * 512 + n] = acc[mf][nf][r] + bc[nf];
            }
        }
    }
}

// ---------------------------------------------------------------------------
// Kernel 2: per-batch Gram via MFMA (unchanged — verified round 8)
// ---------------------------------------------------------------------------
__global__ __launch_bounds__(256) void gram_kernel(
    const float* __restrict__ X,    // [T][B][NX]
    float* __restrict__ Gt)         // [B][64][64]
{
    const int b    = blockIdx.x;
    const int tid  = threadIdx.x;
    const int lane = tid & 63;
    const int w    = tid >> 6;      // wave 0..3

    __shared__ unsigned short xs[4096 * 8];   // 64 KB, fragment order

#pragma unroll
    for (int i = 0; i < 16; ++i) {
        int g   = tid + i * 256;          // 0..4095
        int ks  = g >> 8;
        int ms  = (g >> 6) & 3;
        int l   = g & 63;
        int row = ms * 16 + (l & 15);     // time index t in [0,64)
        int k   = ks * 32 + (l >> 4) * 8;
        const float* src = &X[(size_t)row * (BATCH * NX) + (size_t)b * NX + k];
        float4 v0 = *(const float4*)src;
        float4 v1 = *(const float4*)(src + 4);
        union { __hip_bfloat162 q[4]; int4 pk; } u;
        u.q[0] = __float22bfloat162_rn(make_float2(v0.x, v0.y));
        u.q[1] = __float22bfloat162_rn(make_float2(v0.z, v0.w));
        u.q[2] = __float22bfloat162_rn(make_float2(v1.x, v1.y));
        u.q[3] = __float22bfloat162_rn(make_float2(v1.z, v1.w));
        *(int4*)&xs[g * 8] = u.pk;
    }
    __syncthreads();

    f32x4 acc[4] = {};
#pragma unroll
    for (int ks = 0; ks < 16; ++ks) {
        bf16x8 afr = *(const bf16x8*)&xs[((ks * 4 + w) * 64 + lane) * 8];
#pragma unroll
        for (int nf = 0; nf < 4; ++nf) {
            bf16x8 bfr = *(const bf16x8*)&xs[((ks * 4 + nf) * 64 + lane) * 8];
            acc[nf] = __builtin_amdgcn_mfma_f32_16x16x32_bf16(afr, bfr, acc[nf], 0, 0, 0);
        }
    }

#pragma unroll
    for (int nf = 0; nf < 4; ++nf) {
#pragma unroll
        for (int r = 0; r < 4; ++r) {
            int mrow = w * 16 + ((lane >> 4) << 2) + r;
            int ncol = nf * 16 + (lane & 15);
            Gt[((size_t)b * 64 + mrow) * 64 + ncol] = acc[nf][r];
        }
    }
}

// ---------------------------------------------------------------------------
// 64-lane sum via DPP; result valid in lane 63. (HW-verified rounds 4-8)
// ---------------------------------------------------------------------------
__device__ __forceinline__ float dpp_sum64(float v) {
    v += __int_as_float(__builtin_amdgcn_update_dpp(0, __float_as_int(v), 0x111, 0xf, 0xf, true)); // row_shr:1
    v += __int_as_float(__builtin_amdgcn_update_dpp(0, __float_as_int(v), 0x112, 0xf, 0xf, true)); // row_shr:2
    v += __int_as_float(__builtin_amdgcn_update_dpp(0, __float_as_int(v), 0x114, 0xf, 0xf, true)); // row_shr:4
    v += __int_as_float(__builtin_amdgcn_update_dpp(0, __float_as_int(v), 0x118, 0xf, 0xf, true)); // row_shr:8
    v += __int_as_float(__builtin_amdgcn_update_dpp(0, __float_as_int(v), 0x142, 0xf, 0xf, true)); // row_bcast:15
    v += __int_as_float(__builtin_amdgcn_update_dpp(0, __float_as_int(v), 0x143, 0xf, 0xf, true)); // row_bcast:31
    return v;
}

// ---------------------------------------------------------------------------
// Kernel 3: scan v3 — no global stores on the per-step path.
//   vs round 7 (verified 49.5 us):
//   * outH: batched per-chunk from hcur[16] registers AFTER the chunk's last
//     barrier -> the 16 per-step barriers have zero outstanding VMEM, so the
//     implicit s_waitcnt vmcnt(0) in __syncthreads is free (was ~300-500 cy
//     of exposed store-drain EVERY step).
//   * outY: per-step result -> tiny LDS ys[64][2] (thread 0), ONE cooperative
//     global store at kernel end.
//   * serial-chain coeffs cf[16] prefetched one step early (uniform
//     ds_read_b128 x4 issued pre-barrier, completed by the barrier's lgkm
//     drain) -> post-barrier chain runs on registers; only the red read
//     (~120 cy) remains on the chain.
//   Unchanged (verified): chunk structure, C build, macc burst, DPP reduce,
//   parity red, one barrier per step, Hs column-private layout.
// ---------------------------------------------------------------------------
__global__ __launch_bounds__(512, 1) void scan_kernel(
    const float* __restrict__ P,    // [T][B][NH]  (== outH, aliased)
    const float* __restrict__ Gt,   // [B][64][64]
    const float* __restrict__ w2,   // [NH][2]
    const float* __restrict__ b2,   // [2]
    const float* __restrict__ w21,  // [NH][2]
    const float* __restrict__ lamp,
    const float* __restrict__ etap,
    float* __restrict__ outH,       // [T][B][NH]
    float* __restrict__ outY)       // [T][B][2]
{
    const int b = blockIdx.x;
    const int h = threadIdx.x;

    __shared__ float Hs[64][512];   // 128 KB history; col h private to thread h
    __shared__ float C[16][64];     // current chunk's coefficient matrix
    __shared__ float lam_pow[64];
    __shared__ float red[2][16];
    __shared__ float ys[64][2];     // outY staging (thread 0 writes per step)

    const float eta = etap[0];
    const float lam = fminf(lamp[0], 1.0f);
    const float2 w21v = *(const float2*)&w21[2 * h];
    const float2 w2v  = *(const float2*)&w2[2 * h];
    const float b20 = b2[0], b21 = b2[1];
    const float* gb  = Gt + (size_t)b * 4096;
    const float* Pb  = P + (size_t)b * NH + h;
    float*       oHb = outH + (size_t)b * NH + h;

    if (h < 64)
        lam_pow[h] = (h == 0) ? 1.0f : exp2f((float)h * log2f(lam));
    __syncthreads();   // order lam_pow writes before chunk-0 C-build reads

    float a2x = 0.f, a2y = 0.f;

#pragma unroll 1
    for (int c = 0; c < 4; ++c) {
        const int t0 = c * 16;

        // ---- build C (this chunk): prior reads of C all precede the last
        //      per-step barrier of the previous chunk -> write-after-read safe.
#pragma unroll
        for (int e = h; e < 1024; e += 512) {
            int tt = e >> 6, s = e & 63;
            int t  = t0 + tt;
            float cv = 0.f;
            if (s < t) cv = eta * lam_pow[t - 1 - s] * gb[t * 64 + s];
            C[tt][s] = cv;
        }

        // ---- preload chunk's P (latency covered by C-build + macc burst).
        //      Also: prev chunk's batched outH stores drain at the next
        //      barrier — once per chunk, under this cover.
        float pvreg[16];
#pragma unroll
        for (int tt = 0; tt < 16; ++tt)
            pvreg[tt] = Pb[(size_t)(t0 + tt) * (BATCH * NH)];

        __syncthreads();   // C visible (Hs from prev chunks already barriered)

        // ---- past-chunk history matmul (burst; fully parallel) ----------
        float macc[16] = {};
#pragma unroll 2
        for (int s = 0; s < t0; ++s) {
            float hsv = Hs[s][h];
#pragma unroll
            for (int tt = 0; tt < 16; ++tt)
                macc[tt] = fmaf(C[tt][s], hsv, macc[tt]);
        }

        // ---- 16 sequential steps ----------------------------------------
        float hcur[16];
        float cf[16];
#pragma unroll
        for (int tt = 0; tt < 16; ++tt) {
            const int par = tt & 1;

            // serial chain: cf[] was prefetched into registers last step
            float a1 = pvreg[tt] + w21v.x * a2x + w21v.y * a2y + macc[tt];
#pragma unroll
            for (int j = 0; j < tt; ++j)
                a1 = fmaf(cf[j], hcur[j], a1);

            float hv = 1.0f / (1.0f + __expf(-a1));
            hcur[tt] = hv;
            Hs[t0 + tt][h] = hv;     // LDS only (lgkm, cheap)

            float p0 = dpp_sum64(hv * w2v.x);
            float p1 = dpp_sum64(hv * w2v.y);
            if ((h & 63) == 63) {
                red[par][(h >> 6) * 2]     = p0;
                red[par][(h >> 6) * 2 + 1] = p1;
            }

            // prefetch next step's chain coeffs (uniform b128 reads; complete
            // at the barrier's lgkmcnt(0) drain)
            if (tt < 15) {
#pragma unroll
                for (int q = 0; q < 4; ++q) {
                    float4 v = *(const float4*)&C[tt + 1][t0 + q * 4];
                    cf[q * 4 + 0] = v.x; cf[q * 4 + 1] = v.y;
                    cf[q * 4 + 2] = v.z; cf[q * 4 + 3] = v.w;
                }
            }

            __syncthreads();   // vmcnt=0 outstanding mid-chunk -> cheap drain

            float4 r0 = *(const float4*)&red[par][0];
            float4 r1 = *(const float4*)&red[par][4];
            float4 r2 = *(const float4*)&red[par][8];
            float4 r3 = *(const float4*)&red[par][12];
            float s0 = b20 + ((r0.x + r0.z) + (r1.x + r1.z)) + ((r2.x + r2.z) + (r3.x + r3.z));
            float s1 = b21 + ((r0.y + r0.w) + (r1.y + r1.w)) + ((r2.y + r2.w) + (r3.y + r3.w));
            if (h == 0) {
                ys[t0 + tt][0] = 1.0f / (1.0f + __expf(-s0));
                ys[t0 + tt][1] = 1.0f / (1.0f + __expf(-s1));
            }
            a2x = s0; a2y = s1;
        }

        // ---- batched outH stores for this chunk (registers -> global);
        //      issued once, drained at the next chunk-start barrier.
#pragma unroll
        for (int tt = 0; tt < 16; ++tt)
            oHb[(size_t)(t0 + tt) * (BATCH * NH)] = hcur[tt];
    }

    // ---- final outY store (cooperative, one pass) -----------------------
    __syncthreads();   // order thread-0 ys writes with the readers below
    if (h < 128)
        outY[(size_t)(h >> 1) * (BATCH * 2) + (size_t)b * 2 + (h & 1)] = ys[h >> 1][h & 1];
}

// ---------------------------------------------------------------------------
extern "C" void kernel_launch(void* const* d_in, const int* in_sizes, int n_in,
                              void* d_out, int out_size, void* d_ws, size_t ws_size,
                              hipStream_t stream) {
    const float* x   = (const float*)d_in[0];
    const float* w1  = (const float*)d_in[1];
    const float* b1  = (const float*)d_in[2];
    const float* w2  = (const float*)d_in[3];
    const float* b2  = (const float*)d_in[4];
    const float* w21 = (const float*)d_in[5];
    const float* lam = (const float*)d_in[6];
    const float* eta = (const float*)d_in[7];

    float* outH = (float*)d_out;                       // [64*256*512], doubles as P
    float* outY = outH + (size_t)T_STEPS * BATCH * NH; // [64*256*2]
    float* Gt   = (float*)d_ws;                        // [256*64*64] = 4 MB

    gemm_bf16_kernel<<<dim3(128, 4), 256, 0, stream>>>(x, w1, b1, outH);
    gram_kernel<<<256, 256, 0, stream>>>(x, Gt);
    scan_kernel<<<256, 512, 0, stream>>>(outH, Gt, w2, b2, w21, lam, eta, outH, outY);
}

// Round 10
// 92.371 us; speedup vs baseline: 1.0432x; 1.0432x over previous
//
#include <hip/hip_runtime.h>
#include <hip/hip_bf16.h>
#include <math.h>

#define T_STEPS 64
#define BATCH   256
#define NX      512
#define NH      512

typedef short bf16x8 __attribute__((ext_vector_type(8)));
typedef float f32x4  __attribute__((ext_vector_type(4)));

// ---------------------------------------------------------------------------
// Kernel 1: P[r][h] = b1[h] + sum_k X[r][k] * W1[h][k]   (bf16 MFMA, f32 acc)
//   v2: register-prefetch pipeline. The round-3..9 version staged with
//   load->cvt->ds_write per sub-iteration at VGPR=68, exposing L2/L3 latency
//   ~4x per k-block. Now: all 16 float4 loads for k-block kb+1 are issued
//   right after the LDS-visible barrier and fly under kb's MFMA + barrier;
//   cvt+write consumes them next iteration from registers (T14 pattern).
//   Fragment layout, MFMA section, epilogue unchanged (verified r3-r9).
// ---------------------------------------------------------------------------
__global__ __launch_bounds__(256) void gemm_bf16_kernel(
    const float* __restrict__ X,    // [16384][512]
    const float* __restrict__ W1,   // [512][512]
    const float* __restrict__ b1,   // [512]
    float* __restrict__ P)          // [16384][512]
{
    __shared__ unsigned short lds[16384];   // 32 KB: A = [0,8192), B = [8192,16384)

    const int tid  = threadIdx.x;
    const int lane = tid & 63;
    const int wave = tid >> 6;
    const int wm   = wave >> 1;
    const int wn   = wave & 1;
    const int rbase = blockIdx.x * 128;
    const int nbase = blockIdx.y * 128;

    // staging coordinates for this thread (4 fragment-groups, A and B share them)
    int srow[4], skof[4];
#pragma unroll
    for (int i = 0; i < 4; ++i) {
        int g = tid + i * 256;          // 0..1023
        int ks = g >> 9, ms = (g >> 6) & 7, l = g & 63;
        srow[i] = ms * 16 + (l & 15);
        skof[i] = ks * 32 + (l >> 4) * 8;
    }

    f32x4 acc[4][4] = {};
    float4 ra[4][2], rb[4][2];          // staged k-block (16 float4 = 64 VGPR)

    // prologue: load k-block 0
#pragma unroll
    for (int i = 0; i < 4; ++i) {
        const float* sa = &X [(size_t)(rbase + srow[i]) * 512 + skof[i]];
        const float* sb = &W1[(size_t)(nbase + srow[i]) * 512 + skof[i]];
        ra[i][0] = *(const float4*)sa;  ra[i][1] = *(const float4*)(sa + 4);
        rb[i][0] = *(const float4*)sb;  rb[i][1] = *(const float4*)(sb + 4);
    }

    for (int kb = 0; kb < 512; kb += 64) {
        // ---- convert staged registers -> fragment-ordered LDS ----
#pragma unroll
        for (int i = 0; i < 4; ++i) {
            int g = tid + i * 256;
            union { __hip_bfloat162 q[4]; int4 pk; } ua, ub;
            ua.q[0] = __float22bfloat162_rn(make_float2(ra[i][0].x, ra[i][0].y));
            ua.q[1] = __float22bfloat162_rn(make_float2(ra[i][0].z, ra[i][0].w));
            ua.q[2] = __float22bfloat162_rn(make_float2(ra[i][1].x, ra[i][1].y));
            ua.q[3] = __float22bfloat162_rn(make_float2(ra[i][1].z, ra[i][1].w));
            ub.q[0] = __float22bfloat162_rn(make_float2(rb[i][0].x, rb[i][0].y));
            ub.q[1] = __float22bfloat162_rn(make_float2(rb[i][0].z, rb[i][0].w));
            ub.q[2] = __float22bfloat162_rn(make_float2(rb[i][1].x, rb[i][1].y));
            ub.q[3] = __float22bfloat162_rn(make_float2(rb[i][1].z, rb[i][1].w));
            *(int4*)&lds[g * 8]        = ua.pk;
            *(int4*)&lds[8192 + g * 8] = ub.pk;
        }
        __syncthreads();

        // ---- issue next k-block's loads (fly under MFMA + barrier) ----
        if (kb < 448) {
#pragma unroll
            for (int i = 0; i < 4; ++i) {
                const float* sa = &X [(size_t)(rbase + srow[i]) * 512 + kb + 64 + skof[i]];
                const float* sb = &W1[(size_t)(nbase + srow[i]) * 512 + kb + 64 + skof[i]];
                ra[i][0] = *(const float4*)sa;  ra[i][1] = *(const float4*)(sa + 4);
                rb[i][0] = *(const float4*)sb;  rb[i][1] = *(const float4*)(sb + 4);
            }
        }

        // ---- MFMA: 2 k-slices x (4+4 ds_read_b128 -> 16 MFMA) ----
#pragma unroll
        for (int ks = 0; ks < 2; ++ks) {
            bf16x8 afr[4], bfr[4];
#pragma unroll
            for (int mf = 0; mf < 4; ++mf)
                afr[mf] = *(const bf16x8*)&lds[((ks * 8 + wm * 4 + mf) * 64 + lane) * 8];
#pragma unroll
            for (int nf = 0; nf < 4; ++nf)
                bfr[nf] = *(const bf16x8*)&lds[8192 + ((ks * 8 + wn * 4 + nf) * 64 + lane) * 8];
#pragma unroll
            for (int mf = 0; mf < 4; ++mf)
#pragma unroll
                for (int nf = 0; nf < 4; ++nf)
                    acc[mf][nf] = __builtin_amdgcn_mfma_f32_16x16x32_bf16(
                        afr[mf], bfr[nf], acc[mf][nf], 0, 0, 0);
        }
        __syncthreads();
    }

    float bc[4];
#pragma unroll
    for (int nf = 0; nf < 4; ++nf)
        bc[nf] = b1[nbase + wn * 64 + nf * 16 + (lane & 15)];
#pragma unroll
    for (int mf = 0; mf < 4; ++mf) {
#pragma unroll
        for (int nf = 0; nf < 4; ++nf) {
#pragma unroll
            for (int r = 0; r < 4; ++r) {
                int m = rbase + wm * 64 + mf * 16 + ((lane >> 4) << 2) + r;
                int n = nbase + wn * 64 + nf * 16 + (lane & 15);
                P[(size_t)m * 512 + n] = acc[mf][nf][r] + bc[nf];
            }
        }
    }
}

// ---------------------------------------------------------------------------
// Kernel 2: per-batch Gram via MFMA (unchanged — verified round 8)
// ---------------------------------------------------------------------------
__global__ __launch_bounds__(256) void gram_kernel(
    const float* __restrict__ X,    // [T][B][NX]
    float* __restrict__ Gt)         // [B][64][64]
{
    const int b    = blockIdx.x;
    const int tid  = threadIdx.x;
    const int lane = tid & 63;
    const int w    = tid >> 6;      // wave 0..3

    __shared__ unsigned short xs[4096 * 8];   // 64 KB, fragment order

#pragma unroll
    for (int i = 0; i < 16; ++i) {
        int g   = tid + i * 256;          // 0..4095
        int ks  = g >> 8;
        int ms  = (g >> 6) & 3;
        int l   = g & 63;
        int row = ms * 16 + (l & 15);     // time index t in [0,64)
        int k   = ks * 32 + (l >> 4) * 8;
        const float* src = &X[(size_t)row * (BATCH * NX) + (size_t)b * NX + k];
        float4 v0 = *(const float4*)src;
        float4 v1 = *(const float4*)(src + 4);
        union { __hip_bfloat162 q[4]; int4 pk; } u;
        u.q[0] = __float22bfloat162_rn(make_float2(v0.x, v0.y));
        u.q[1] = __float22bfloat162_rn(make_float2(v0.z, v0.w));
        u.q[2] = __float22bfloat162_rn(make_float2(v1.x, v1.y));
        u.q[3] = __float22bfloat162_rn(make_float2(v1.z, v1.w));
        *(int4*)&xs[g * 8] = u.pk;
    }
    __syncthreads();

    f32x4 acc[4] = {};
#pragma unroll
    for (int ks = 0; ks < 16; ++ks) {
        bf16x8 afr = *(const bf16x8*)&xs[((ks * 4 + w) * 64 + lane) * 8];
#pragma unroll
        for (int nf = 0; nf < 4; ++nf) {
            bf16x8 bfr = *(const bf16x8*)&xs[((ks * 4 + nf) * 64 + lane) * 8];
            acc[nf] = __builtin_amdgcn_mfma_f32_16x16x32_bf16(afr, bfr, acc[nf], 0, 0, 0);
        }
    }

#pragma unroll
    for (int nf = 0; nf < 4; ++nf) {
#pragma unroll
        for (int r = 0; r < 4; ++r) {
            int mrow = w * 16 + ((lane >> 4) << 2) + r;
            int ncol = nf * 16 + (lane & 15);
            Gt[((size_t)b * 64 + mrow) * 64 + ncol] = acc[nf][r];
        }
    }
}

// ---------------------------------------------------------------------------
// 64-lane sum via DPP; result valid in lane 63. (HW-verified rounds 4-9)
// ---------------------------------------------------------------------------
__device__ __forceinline__ float dpp_sum64(float v) {
    v += __int_as_float(__builtin_amdgcn_update_dpp(0, __float_as_int(v), 0x111, 0xf, 0xf, true)); // row_shr:1
    v += __int_as_float(__builtin_amdgcn_update_dpp(0, __float_as_int(v), 0x112, 0xf, 0xf, true)); // row_shr:2
    v += __int_as_float(__builtin_amdgcn_update_dpp(0, __float_as_int(v), 0x114, 0xf, 0xf, true)); // row_shr:4
    v += __int_as_float(__builtin_amdgcn_update_dpp(0, __float_as_int(v), 0x118, 0xf, 0xf, true)); // row_shr:8
    v += __int_as_float(__builtin_amdgcn_update_dpp(0, __float_as_int(v), 0x142, 0xf, 0xf, true)); // row_bcast:15
    v += __int_as_float(__builtin_amdgcn_update_dpp(0, __float_as_int(v), 0x143, 0xf, 0xf, true)); // row_bcast:31
    return v;
}

// ---------------------------------------------------------------------------
// Kernel 3: scan — round-7 version EXACTLY (best measured: 49.5 us).
//   Round 9's "no per-step global stores" variant measured 51.0 us ->
//   reverted; per-step outH stores overlap fine.
// ---------------------------------------------------------------------------
__global__ __launch_bounds__(512, 1) void scan_kernel(
    const float* __restrict__ P,    // [T][B][NH]  (== outH, aliased)
    const float* __restrict__ Gt,   // [B][64][64]
    const float* __restrict__ w2,   // [NH][2]
    const float* __restrict__ b2,   // [2]
    const float* __restrict__ w21,  // [NH][2]
    const float* __restrict__ lamp,
    const float* __restrict__ etap,
    float* __restrict__ outH,       // [T][B][NH]
    float* __restrict__ outY)       // [T][B][2]
{
    const int b = blockIdx.x;
    const int h = threadIdx.x;

    __shared__ float Hs[64][512];   // 128 KB history; col h private to thread h
    __shared__ float C[16][64];     // per-chunk coefficient matrix
    __shared__ float lam_pow[64];
    __shared__ float red[2][16];

    const float eta = etap[0];
    const float lam = fminf(lamp[0], 1.0f);
    const float2 w21v = *(const float2*)&w21[2 * h];
    const float2 w2v  = *(const float2*)&w2[2 * h];
    const float b20 = b2[0], b21 = b2[1];
    const float* gb  = Gt + (size_t)b * 4096;
    const float* Pb  = P + (size_t)b * NH + h;
    float*       oHb = outH + (size_t)b * NH + h;

    if (h < 64)
        lam_pow[h] = (h == 0) ? 1.0f : exp2f((float)h * log2f(lam));
    __syncthreads();   // order lam_pow writes before chunk-0 C-build reads

    float a2x = 0.f, a2y = 0.f;

    for (int c = 0; c < 4; ++c) {
        const int t0 = c * 16;

        // ---- build C cooperatively: 1024 entries, 2 per thread ----------
#pragma unroll
        for (int e = h; e < 1024; e += 512) {
            int tt = e >> 6, s = e & 63;
            int t  = t0 + tt;
            float cv = 0.f;
            if (s < t) cv = eta * lam_pow[t - 1 - s] * gb[t * 64 + s];
            C[tt][s] = cv;
        }
        __syncthreads();

        // ---- preload chunk's P (16 coalesced loads, covered by matmul) ---
        float pvreg[16];
#pragma unroll
        for (int tt = 0; tt < 16; ++tt)
            pvreg[tt] = Pb[(size_t)(t0 + tt) * (BATCH * NH)];

        // ---- past-chunk history matmul ----------------------------------
        float macc[16] = {};
#pragma unroll 2
        for (int s = 0; s < t0; ++s) {
            float hsv = Hs[s][h];
#pragma unroll
            for (int tt = 0; tt < 16; ++tt)
                macc[tt] = fmaf(C[tt][s], hsv, macc[tt]);
        }

        // ---- 16 sequential steps ----------------------------------------
        float hcur[16];
#pragma unroll
        for (int tt = 0; tt < 16; ++tt) {
            const int t   = t0 + tt;
            const int par = tt & 1;

            float a1 = pvreg[tt] + w21v.x * a2x + w21v.y * a2y + macc[tt];
#pragma unroll
            for (int j = 0; j < tt; ++j)
                a1 = fmaf(C[tt][t0 + j], hcur[j], a1);

            float hv = 1.0f / (1.0f + __expf(-a1));
            hcur[tt] = hv;
            Hs[t][h] = hv;
            oHb[(size_t)t * (BATCH * NH)] = hv;

            float p0 = dpp_sum64(hv * w2v.x);
            float p1 = dpp_sum64(hv * w2v.y);
            if ((h & 63) == 63) {
                red[par][(h >> 6) * 2]     = p0;
                red[par][(h >> 6) * 2 + 1] = p1;
            }
            __syncthreads();

            float4 r0 = *(const float4*)&red[par][0];
            float4 r1 = *(const float4*)&red[par][4];
            float4 r2 = *(const float4*)&red[par][8];
            float4 r3 = *(const float4*)&red[par][12];
            float s0 = b20 + ((r0.x + r0.z) + (r1.x + r1.z)) + ((r2.x + r2.z) + (r3.x + r3.z));
            float s1 = b21 + ((r0.y + r0.w) + (r1.y + r1.w)) + ((r2.y + r2.w) + (r3.y + r3.w));
            if (h == 0) {
                outY[((size_t)t * BATCH + b) * 2 + 0] = 1.0f / (1.0f + __expf(-s0));
                outY[((size_t)t * BATCH + b) * 2 + 1] = 1.0f / (1.0f + __expf(-s1));
            }
            a2x = s0; a2y = s1;
        }
    }
}

// ---------------------------------------------------------------------------
extern "C" void kernel_launch(void* const* d_in, const int* in_sizes, int n_in,
                              void* d_out, int out_size, void* d_ws, size_t ws_size,
                              hipStream_t stream) {
    const float* x   = (const float*)d_in[0];
    const float* w1  = (const float*)d_in[1];
    const float* b1  = (const float*)d_in[2];
    const float* w2  = (const float*)d_in[3];
    const float* b2  = (const float*)d_in[4];
    const float* w21 = (const float*)d_in[5];
    const float* lam = (const float*)d_in[6];
    const float* eta = (const float*)d_in[7];

    float* outH = (float*)d_out;                       // [64*256*512], doubles as P
    float* outY = outH + (size_t)T_STEPS * BATCH * NH; // [64*256*2]
    float* Gt   = (float*)d_ws;                        // [256*64*64] = 4 MB

    gemm_bf16_kernel<<<dim3(128, 4), 256, 0, stream>>>(x, w1, b1, outH);
    gram_kernel<<<256, 256, 0, stream>>>(x, Gt);
    scan_kernel<<<256, 512, 0, stream>>>(outH, Gt, w2, b2, w21, lam, eta, outH, outY);
}